// Round 3
// baseline (1584.739 us; speedup 1.0000x reference)
//
#include <hip/hip_runtime.h>

// SimpleRNN (relu) scan: B=512, T=512, D=64, H=512, O=1.
// R3: R2 structure + FORCED register-resident weights.
//  - 32 groups x 16 batch rows; each group = 2 WGs (s=0: cols 0..255, s=1: 256..511).
//  - Each WG holds its W slice (576x256 bf16) in 144 VGPRs/lane, pinned via an
//    opaque asm pass (prevents rematerialization-spill seen in R2: VGPR_Count=100).
//  - __launch_bounds__(512,2): 2 waves/EU -> 256-VGPR budget.
//  - Peer h exchange via global hbuf + flags; poll+DMA issued BEFORE phase-1 so
//    the cross-CU latency hides under own-column MFMAs.

#define T_STEPS 512
#define D_IN    64
#define ROWS    16
#define THREADS 512

#define WT_OFF    0
#define WT_BYTES  (512*576*2)            // 589824
#define HBUF_OFF  WT_BYTES
#define HBUF_BYTES (32*2*2*8192)         // 1 MiB
#define FLAGS_OFF (HBUF_OFF + HBUF_BYTES)
#define FLAGS_BYTES (32*2*512*4)         // 128 KiB

typedef float  floatx4 __attribute__((ext_vector_type(4)));
typedef __bf16 bf16x8  __attribute__((ext_vector_type(8)));

#define KEEP4(v) asm volatile("" : "+v"(v))

__device__ __forceinline__ unsigned short f2b(float f) {
    union { float f; unsigned int u; } v; v.f = f;
    unsigned int u = v.u;
    return (unsigned short)((u + 0x7FFFu + ((u >> 16) & 1u)) >> 16);  // RNE
}

// WT element f = ((ng*18 + kc)*64 + lane)*8 + j  encodes B[k][n]:
//   n = ng*16 + (lane&15),  k = kc*32 + (lane>>4)*8 + j
__global__ void prep_kernel(const float* __restrict__ Wx, const float* __restrict__ Wh,
                            unsigned short* __restrict__ WT) {
    int f = blockIdx.x * 256 + threadIdx.x;
    if (f >= 512 * 576) return;
    int j    = f & 7;
    int lane = (f >> 3) & 63;
    int blk  = f >> 9;
    int kc   = blk % 18;
    int ng   = blk / 18;
    int n = ng * 16 + (lane & 15);
    int k = kc * 32 + (lane >> 4) * 8 + j;
    float val = (k < 64) ? Wx[k * 512 + n] : Wh[(k - 64) * 512 + n];
    WT[f] = f2b(val);
}

__global__ __launch_bounds__(THREADS, 2)
void rnn_scan_kernel(const float* __restrict__ x, const unsigned short* __restrict__ WT,
                     const float* __restrict__ b_rnn, const float* __restrict__ Wd,
                     const float* __restrict__ bd, float* __restrict__ out,
                     unsigned short* __restrict__ hbuf, int* __restrict__ flags) {
    // afrag[(kc*64 + lane)*8 + j]: A[m = lane&15, k = kc*32 + (lane>>4)*8 + j]
    // kc 0..1 = x_t (k<64); kc 2..9 = h cols 0..255; kc 10..17 = h cols 256..511.
    __shared__ __attribute__((aligned(16))) unsigned short afrag[18 * 512]; // 18 KB

    const int tid  = threadIdx.x;
    const int lane = tid & 63;
    const int w    = tid >> 6;
    const int c    = lane & 15;
    const int quad = lane >> 4;
    const int g     = blockIdx.x & 31;
    const int s     = blockIdx.x >> 5;
    const int speer = 1 - s;
    const int r0    = g * ROWS;

    // ---- weights -> registers (slot order: 0..1 = x-part, 2..9 = own, 10..17 = peer K) ----
    floatx4 wregf[18][2];
#pragma unroll
    for (int i = 0; i < 18; ++i) {
        const int kcp = (i < 2) ? i : (i < 10 ? (2 + s * 8 + (i - 2))
                                              : (2 + speer * 8 + (i - 10)));
#pragma unroll
        for (int nt = 0; nt < 2; ++nt) {
            const int ng = s * 16 + w * 2 + nt;
            wregf[i][nt] = *reinterpret_cast<const floatx4*>(
                WT + (((size_t)ng * 18 + kcp) * 64 + lane) * 8);
        }
    }
    // pin: opaque redefinition -> cannot be rematerialized as an L2 reload
#pragma unroll
    for (int i = 0; i < 18; ++i) {
        KEEP4(wregf[i][0]);
        KEEP4(wregf[i][1]);
    }

    float bias[2];
#pragma unroll
    for (int nt = 0; nt < 2; ++nt)
        bias[nt] = b_rnn[s * 256 + w * 32 + nt * 16 + c];

    // zero h region, stage x_0
    for (int i = tid; i < 8192; i += THREADS) afrag[1024 + i] = 0;
    const int xe = tid * 2;
    const int xm = xe >> 6;
    const int xk = xe & 63;
    const int xidx = ((xk >> 5) * 64 + ((xk >> 3) & 3) * 16 + xm) * 8 + (xk & 7);
    const float* xbase = x + ((size_t)(r0 + xm) * T_STEPS) * D_IN + xk;
    {
        float f0 = xbase[0], f1 = xbase[1];
        *reinterpret_cast<unsigned int*>(&afrag[xidx]) =
            (unsigned int)f2b(f0) | ((unsigned int)f2b(f1) << 16);
    }
    __syncthreads();

    const char* ab = (const char*)afrag;
    const unsigned laneoff = (unsigned)lane * 16u;
    const unsigned ownB  = laneoff + (unsigned)s * 8192u;      // + i*1024, i in [2,10)
    const unsigned peerB = laneoff + (unsigned)speer * 8192u;  // + (i-8)*1024, i in [10,18)
    const int peerLdsByte = (2 + speer * 8) * 1024;
    const int ownLds = (2 + s * 8) * 512;   // short index base

    int soff[2];
#pragma unroll
    for (int nt = 0; nt < 2; ++nt) {
        const int cl = w * 32 + nt * 16 + c;
        soff[nt] = (((cl >> 5) * 64) + (((cl >> 3) & 3) * 16) + quad * 4) * 8 + (cl & 7);
    }

    for (int t = 0; t < T_STEPS; ++t) {
        // wave 0: poll for peer h_{t-1}, issue 8KB DMA into LDS peer region.
        // No wait here -- latency hides under phase-1 compute.
        if (w == 0 && t > 0) {
            const int* fp = flags + (g * 2 + speer) * 512 + (t - 1);
            if (lane == 0) {
                int gd = 0;
                while (__hip_atomic_load(fp, __ATOMIC_RELAXED, __HIP_MEMORY_SCOPE_AGENT) == 0
                       && ++gd < (1 << 25)) {}
            }
            __builtin_amdgcn_fence(__ATOMIC_ACQUIRE, "agent");
            const char* gp = (const char*)(hbuf + ((size_t)g * 4 + ((t - 1) & 1) * 2 + speer) * 4096)
                             + laneoff;
#pragma unroll
            for (int q = 0; q < 8; ++q)
                __builtin_amdgcn_global_load_lds(
                    (const __attribute__((address_space(1))) unsigned int*)(gp + q * 1024),
                    (__attribute__((address_space(3))) unsigned int*)((char*)afrag + peerLdsByte + q * 1024),
                    16, 0, 0);
        }

        float xf0 = 0.f, xf1 = 0.f;
        if (t < T_STEPS - 1) {
            const float* xp = xbase + (size_t)(t + 1) * D_IN;
            xf0 = xp[0]; xf1 = xp[1];
        }

        floatx4 acc0 = {0.f, 0.f, 0.f, 0.f}, acc1 = {0.f, 0.f, 0.f, 0.f};

        // phase 1: x + own columns (no peer data needed)
#pragma unroll
        for (int i = 0; i < 2; ++i) {
            bf16x8 a = *reinterpret_cast<const bf16x8*>(ab + laneoff + i * 1024);
            acc0 = __builtin_amdgcn_mfma_f32_16x16x32_bf16(a, __builtin_bit_cast(bf16x8, wregf[i][0]), acc0, 0, 0, 0);
            acc1 = __builtin_amdgcn_mfma_f32_16x16x32_bf16(a, __builtin_bit_cast(bf16x8, wregf[i][1]), acc1, 0, 0, 0);
        }
#pragma unroll
        for (int i = 2; i < 10; ++i) {
            bf16x8 a = *reinterpret_cast<const bf16x8*>(ab + ownB + i * 1024);
            acc0 = __builtin_amdgcn_mfma_f32_16x16x32_bf16(a, __builtin_bit_cast(bf16x8, wregf[i][0]), acc0, 0, 0, 0);
            acc1 = __builtin_amdgcn_mfma_f32_16x16x32_bf16(a, __builtin_bit_cast(bf16x8, wregf[i][1]), acc1, 0, 0, 0);
        }

        // drain DMA (wave 0 only has outstanding LDS-dest loads)
        if (w == 0 && t > 0)
            asm volatile("s_waitcnt vmcnt(0)" ::: "memory");
        __syncthreads();

        // phase 2: peer columns
#pragma unroll
        for (int i = 10; i < 18; ++i) {
            bf16x8 a = *reinterpret_cast<const bf16x8*>(ab + peerB + (i - 8) * 1024);
            acc0 = __builtin_amdgcn_mfma_f32_16x16x32_bf16(a, __builtin_bit_cast(bf16x8, wregf[i][0]), acc0, 0, 0, 0);
            acc1 = __builtin_amdgcn_mfma_f32_16x16x32_bf16(a, __builtin_bit_cast(bf16x8, wregf[i][1]), acc1, 0, 0, 0);
        }

        // epilogue: relu+pack h_t -> own LDS region + global slice (A-frag order)
        unsigned short* hs = hbuf + ((size_t)g * 4 + (t & 1) * 2 + s) * 4096;
#pragma unroll
        for (int nt = 0; nt < 2; ++nt) {
#pragma unroll
            for (int r = 0; r < 4; ++r) {
                float v = (nt ? acc1[r] : acc0[r]) + bias[nt];
                v = v > 0.f ? v : 0.f;
                const unsigned short hb = f2b(v);
                const int so = soff[nt] + r * 8;
                afrag[ownLds + so] = hb;
                hs[so] = hb;
            }
        }
        if (t < T_STEPS - 1)
            *reinterpret_cast<unsigned int*>(&afrag[xidx]) =
                (unsigned int)f2b(xf0) | ((unsigned int)f2b(xf1) << 16);
        __syncthreads();   // drains all waves' global stores (vmcnt(0) before s_barrier)
        if (tid == 0)
            __hip_atomic_store(flags + (g * 2 + s) * 512 + t, 1,
                               __ATOMIC_RELEASE, __HIP_MEMORY_SCOPE_AGENT);
    }

    // ---- output head: only s==0 finalizes (needs peer h_511 slice) ----
    if (s == 0) {
        if (w == 0) {
            const int* fp = flags + (g * 2 + 1) * 512 + 511;
            if (lane == 0) {
                int gd = 0;
                while (__hip_atomic_load(fp, __ATOMIC_RELAXED, __HIP_MEMORY_SCOPE_AGENT) == 0
                       && ++gd < (1 << 25)) {}
            }
            __builtin_amdgcn_fence(__ATOMIC_ACQUIRE, "agent");
            const char* gp = (const char*)(hbuf + ((size_t)g * 4 + 1 * 2 + 1) * 4096) + laneoff;
#pragma unroll
            for (int q = 0; q < 8; ++q)
                __builtin_amdgcn_global_load_lds(
                    (const __attribute__((address_space(1))) unsigned int*)(gp + q * 1024),
                    (__attribute__((address_space(3))) unsigned int*)((char*)afrag + 10240 + q * 1024),
                    16, 0, 0);
            asm volatile("s_waitcnt vmcnt(0)" ::: "memory");
        }
        __syncthreads();

        const int lane5 = lane & 31;
        const int row = w * 2 + (lane >> 5);
        float sum = 0.f;
#pragma unroll
        for (int b2 = 0; b2 < 2; ++b2) {
            const int col0 = lane5 * 16 + b2 * 8;
            const int kcp = 2 + (col0 >> 5);
            const int q2 = (col0 >> 3) & 3;
            const bf16x8 hvv = *reinterpret_cast<const bf16x8*>(&afrag[kcp * 512 + (q2 * 16 + row) * 8]);
#pragma unroll
            for (int jj = 0; jj < 8; ++jj)
                sum += (float)hvv[jj] * Wd[col0 + jj];
        }
#pragma unroll
        for (int off = 1; off < 32; off <<= 1) sum += __shfl_xor(sum, off, 64);
        if (lane5 == 0) {
            float v = sum + bd[0];
            out[r0 + row] = v > 0.f ? v : 0.f;
        }
    }
}

extern "C" void kernel_launch(void* const* d_in, const int* in_sizes, int n_in,
                              void* d_out, int out_size, void* d_ws, size_t ws_size,
                              hipStream_t stream) {
    const float* x    = (const float*)d_in[0];
    const float* Wx   = (const float*)d_in[1];
    const float* Wh   = (const float*)d_in[2];
    const float* brnn = (const float*)d_in[3];
    const float* Wd   = (const float*)d_in[4];
    const float* bd   = (const float*)d_in[5];
    float* out = (float*)d_out;

    char* wsb = (char*)d_ws;
    unsigned short* WT   = (unsigned short*)(wsb + WT_OFF);
    unsigned short* hbuf = (unsigned short*)(wsb + HBUF_OFF);
    int*            flg  = (int*)(wsb + FLAGS_OFF);

    hipMemsetAsync(wsb + FLAGS_OFF, 0, FLAGS_BYTES, stream);
    prep_kernel<<<(512 * 576 + 255) / 256, 256, 0, stream>>>(Wx, Wh, WT);
    rnn_scan_kernel<<<64, THREADS, 0, stream>>>(x, WT, brnn, Wd, bd, out, hbuf, flg);
}